// Round 1
// baseline (566.830 us; speedup 1.0000x reference)
//
#include <hip/hip_runtime.h>

#define TT 4
#define BB 32
#define CC 384
#define NN 256
#define NHEADS 8
#define CHD 48      // CC / NHEADS
#define KC 64       // K-chunk
#define LSTR 68     // LDS row stride (floats), padded, 16B-aligned (68*4=272)

// ---------------------------------------------------------------------------
// Kernel A: fused  q/k 1x1-conv (GEMM) + BN + LIF  +  head-sum -> attn LIF
//           + y = attn * k_spike  (y stored as uint8 {0,1})
// grid: B * NHEADS * (NN/64) = 32*8*4 = 1024 blocks, 256 threads
// block tile: 48 d (one head) x 64 n, thread tile 3d x 4n
// ---------------------------------------------------------------------------
__global__ __launch_bounds__(256) void qk_fused(
    const float* __restrict__ x,
    const float* __restrict__ qw, const float* __restrict__ qg,
    const float* __restrict__ qbe, const float* __restrict__ qm,
    const float* __restrict__ qva,
    const float* __restrict__ kw, const float* __restrict__ kg,
    const float* __restrict__ kbe, const float* __restrict__ km,
    const float* __restrict__ kva,
    unsigned char* __restrict__ y)
{
    __shared__ float xs[KC * LSTR];     // x chunk  [c][n]
    __shared__ float qws[CHD * LSTR];   // q_w rows [d][c]
    __shared__ float kws[CHD * LSTR];   // k_w rows [d][c]
    __shared__ float hsum[16 * 64];     // partial head sums [dg][n]

    const int tid  = threadIdx.x;
    const int bid  = blockIdx.x;
    const int b    = bid >> 5;
    const int head = (bid >> 2) & 7;
    const int n0   = (bid & 3) << 6;

    const int dg = tid >> 4;          // 0..15, 3 d's each
    const int nl = (tid & 15) << 2;   // 0..60, 4 n's each

    // BN constants for this thread's 3 output channels per branch
    float q_inv[3], q_mu[3], q_b[3], k_inv[3], k_mu[3], k_b[3];
#pragma unroll
    for (int i = 0; i < 3; ++i) {
        int d = head * CHD + dg * 3 + i;
        q_inv[i] = qg[d] / sqrtf(qva[d] + 1e-5f);
        q_mu[i]  = qm[d];  q_b[i] = qbe[d];
        k_inv[i] = kg[d] / sqrtf(kva[d] + 1e-5f);
        k_mu[i]  = km[d];  k_b[i] = kbe[d];
    }

    // LIF states (persist across t)
    float vq[3][4], vk[3][4], va[4];
#pragma unroll
    for (int i = 0; i < 3; ++i)
#pragma unroll
        for (int j = 0; j < 4; ++j) { vq[i][j] = 0.f; vk[i][j] = 0.f; }
#pragma unroll
    for (int j = 0; j < 4; ++j) va[j] = 0.f;

    for (int t = 0; t < TT; ++t) {
        float accq[3][4] = {};
        float acck[3][4] = {};

        for (int kc = 0; kc < CC / KC; ++kc) {
            const int c0 = kc * KC;
            __syncthreads();   // protect LDS from readers of previous chunk
            // stage x chunk: 64 rows x 64 floats = 1024 float4, 4 per thread
#pragma unroll
            for (int p = 0; p < 4; ++p) {
                int q4 = tid + p * 256;
                int cc = q4 >> 4, nn = (q4 & 15) << 2;
                *(float4*)&xs[cc * LSTR + nn] =
                    *(const float4*)&x[((t * BB + b) * CC + c0 + cc) * NN + n0 + nn];
            }
            // stage weight chunks: 48 rows x 64 = 768 float4 each, 3 per thread
#pragma unroll
            for (int p = 0; p < 3; ++p) {
                int q4 = tid + p * 256;
                int dl = q4 >> 4, cc = (q4 & 15) << 2;
                *(float4*)&qws[dl * LSTR + cc] =
                    *(const float4*)&qw[(head * CHD + dl) * CC + c0 + cc];
                *(float4*)&kws[dl * LSTR + cc] =
                    *(const float4*)&kw[(head * CHD + dl) * CC + c0 + cc];
            }
            __syncthreads();
            // GEMM on the chunk: per c-quad 10 b128 LDS reads, 96 FMAs
#pragma unroll
            for (int cq = 0; cq < KC / 4; ++cq) {
                float xv[4][4];
#pragma unroll
                for (int u = 0; u < 4; ++u)
                    *(float4*)&xv[u][0] = *(const float4*)&xs[(cq * 4 + u) * LSTR + nl];
#pragma unroll
                for (int i = 0; i < 3; ++i) {
                    float qv[4], kv[4];
                    *(float4*)&qv[0] = *(const float4*)&qws[(dg * 3 + i) * LSTR + cq * 4];
                    *(float4*)&kv[0] = *(const float4*)&kws[(dg * 3 + i) * LSTR + cq * 4];
#pragma unroll
                    for (int u = 0; u < 4; ++u)
#pragma unroll
                        for (int j = 0; j < 4; ++j) {
                            accq[i][j] = fmaf(qv[u], xv[u][j], accq[i][j]);
                            acck[i][j] = fmaf(kv[u], xv[u][j], acck[i][j]);
                        }
                }
            }
        }

        // ---- epilogue for this t: BN + LIF for q and k ----
        float part[4] = {0.f, 0.f, 0.f, 0.f};
        float ks[3][4];
#pragma unroll
        for (int i = 0; i < 3; ++i)
#pragma unroll
            for (int j = 0; j < 4; ++j) {
                // q branch
                float bnq = (accq[i][j] - q_mu[i]) * q_inv[i] + q_b[i];
                float hq  = vq[i][j] + (bnq - vq[i][j]) * 0.5f;
                float sq  = (hq - 1.0f >= 0.0f) ? 1.0f : 0.0f;
                vq[i][j]  = hq * (1.0f - sq);
                part[j]  += sq;
                // k branch
                float bnk = (acck[i][j] - k_mu[i]) * k_inv[i] + k_b[i];
                float hk  = vk[i][j] + (bnk - vk[i][j]) * 0.5f;
                float sk  = (hk - 1.0f >= 0.0f) ? 1.0f : 0.0f;
                vk[i][j]  = hk * (1.0f - sk);
                ks[i][j]  = sk;
            }
        // head-sum reduction across the 16 d-groups
#pragma unroll
        for (int j = 0; j < 4; ++j) hsum[dg * 64 + nl + j] = part[j];
        __syncthreads();
        float attn[4];
#pragma unroll
        for (int j = 0; j < 4; ++j) {
            float tot = 0.f;
#pragma unroll
            for (int g = 0; g < 16; ++g) tot += hsum[g * 64 + nl + j];
            // attn LIF (v_threshold = 0.5); exact in fp32 (tot is a small int)
            float ha = va[j] + (tot - va[j]) * 0.5f;
            float sa = (ha - 0.5f >= 0.0f) ? 1.0f : 0.0f;
            va[j]   = ha * (1.0f - sa);
            attn[j] = sa;
        }
        // y = attn * k_spike, uint8
#pragma unroll
        for (int i = 0; i < 3; ++i) {
            uchar4 yo;
            yo.x = (unsigned char)(attn[0] * ks[i][0]);
            yo.y = (unsigned char)(attn[1] * ks[i][1]);
            yo.z = (unsigned char)(attn[2] * ks[i][2]);
            yo.w = (unsigned char)(attn[3] * ks[i][3]);
            *(uchar4*)&y[((t * BB + b) * CC + head * CHD + dg * 3 + i) * NN + n0 + nl] = yo;
        }
    }
}

// ---------------------------------------------------------------------------
// Kernel B: proj GEMM (binary y input) + bias + BN + LIF -> output spikes
// grid: B * (CC/64) * (NN/64) = 32*6*4 = 768 blocks, 256 threads
// block tile: 64 d x 64 n, thread tile 4d x 4n
// ---------------------------------------------------------------------------
__global__ __launch_bounds__(256) void proj_fused(
    const unsigned char* __restrict__ yin,
    const float* __restrict__ pw, const float* __restrict__ pg,
    const float* __restrict__ pbe, const float* __restrict__ pm,
    const float* __restrict__ pva, const float* __restrict__ pbias,
    float* __restrict__ out)
{
    __shared__ float ys[KC * LSTR];
    __shared__ float pws[64 * LSTR];

    const int tid = threadIdx.x;
    const int bid = blockIdx.x;
    const int b   = bid / 24;
    const int r   = bid % 24;
    const int d0  = (r >> 2) * 64;
    const int n0  = (r & 3) << 6;

    const int dg = tid >> 4;          // 0..15, 4 d's each
    const int nl = (tid & 15) << 2;

    float inv[4], mu[4], be[4], bi[4];
#pragma unroll
    for (int i = 0; i < 4; ++i) {
        int d  = d0 + dg * 4 + i;
        inv[i] = pg[d] / sqrtf(pva[d] + 1e-5f);
        mu[i]  = pm[d]; be[i] = pbe[d]; bi[i] = pbias[d];
    }

    float vv[4][4];
#pragma unroll
    for (int i = 0; i < 4; ++i)
#pragma unroll
        for (int j = 0; j < 4; ++j) vv[i][j] = 0.f;

    for (int t = 0; t < TT; ++t) {
        float acc[4][4] = {};
        for (int kc = 0; kc < CC / KC; ++kc) {
            const int c0 = kc * KC;
            __syncthreads();
#pragma unroll
            for (int p = 0; p < 4; ++p) {
                int q4 = tid + p * 256;
                int cc = q4 >> 4, nn = (q4 & 15) << 2;
                unsigned int w =
                    *(const unsigned int*)&yin[((t * BB + b) * CC + c0 + cc) * NN + n0 + nn];
                ys[cc * LSTR + nn + 0] = (float)(w & 0xff);
                ys[cc * LSTR + nn + 1] = (float)((w >> 8) & 0xff);
                ys[cc * LSTR + nn + 2] = (float)((w >> 16) & 0xff);
                ys[cc * LSTR + nn + 3] = (float)(w >> 24);
                *(float4*)&pws[cc * LSTR + nn] =
                    *(const float4*)&pw[(d0 + cc) * CC + c0 + nn];
            }
            __syncthreads();
#pragma unroll
            for (int cq = 0; cq < KC / 4; ++cq) {
                float xv[4][4];
#pragma unroll
                for (int u = 0; u < 4; ++u)
                    *(float4*)&xv[u][0] = *(const float4*)&ys[(cq * 4 + u) * LSTR + nl];
#pragma unroll
                for (int i = 0; i < 4; ++i) {
                    float pv[4];
                    *(float4*)&pv[0] = *(const float4*)&pws[(dg * 4 + i) * LSTR + cq * 4];
#pragma unroll
                    for (int u = 0; u < 4; ++u)
#pragma unroll
                        for (int j = 0; j < 4; ++j)
                            acc[i][j] = fmaf(pv[u], xv[u][j], acc[i][j]);
                }
            }
        }
        // bias + BN + LIF + store
#pragma unroll
        for (int i = 0; i < 4; ++i) {
            float res[4];
#pragma unroll
            for (int j = 0; j < 4; ++j) {
                float z   = acc[i][j] + bi[i];
                float bnv = (z - mu[i]) * inv[i] + be[i];
                float h   = vv[i][j] + (bnv - vv[i][j]) * 0.5f;
                float s   = (h - 1.0f >= 0.0f) ? 1.0f : 0.0f;
                vv[i][j]  = h * (1.0f - s);
                res[j]    = s;
            }
            *(float4*)&out[((t * BB + b) * CC + d0 + dg * 4 + i) * NN + n0 + nl] =
                *(float4*)&res[0];
        }
    }
}

extern "C" void kernel_launch(void* const* d_in, const int* in_sizes, int n_in,
                              void* d_out, int out_size, void* d_ws, size_t ws_size,
                              hipStream_t stream)
{
    const float* x     = (const float*)d_in[0];
    const float* qw    = (const float*)d_in[1];
    const float* qg    = (const float*)d_in[2];
    const float* qbe   = (const float*)d_in[3];
    const float* qm    = (const float*)d_in[4];
    const float* qva   = (const float*)d_in[5];
    const float* kw    = (const float*)d_in[6];
    const float* kg    = (const float*)d_in[7];
    const float* kbe   = (const float*)d_in[8];
    const float* km    = (const float*)d_in[9];
    const float* kva   = (const float*)d_in[10];
    const float* pw    = (const float*)d_in[11];
    const float* pg    = (const float*)d_in[12];
    const float* pbe   = (const float*)d_in[13];
    const float* pm    = (const float*)d_in[14];
    const float* pva   = (const float*)d_in[15];
    const float* pbias = (const float*)d_in[16];

    unsigned char* y = (unsigned char*)d_ws;   // TT*BB*CC*NN = 12.6 MB
    float* out = (float*)d_out;

    qk_fused<<<BB * NHEADS * (NN / 64), 256, 0, stream>>>(
        x, qw, qg, qbe, qm, qva, kw, kg, kbe, km, kva, y);
    proj_fused<<<BB * (CC / 64) * (NN / 64), 256, 0, stream>>>(
        y, pw, pg, pbe, pm, pva, pbias, out);
}

// Round 2
// 264.481 us; speedup vs baseline: 2.1432x; 2.1432x over previous
//
#include <hip/hip_runtime.h>

typedef _Float16 f16x8 __attribute__((ext_vector_type(8)));
typedef _Float16 f16x4 __attribute__((ext_vector_type(4)));
typedef float    f32x4 __attribute__((ext_vector_type(4)));

#define TT 4
#define BB 32
#define CC 384
#define NN 256

// ---- ws layout (bytes) ----
// x0  f16 [t][b][n][c] : 0          .. 25165824
// x1  f16 [t][b][n][c] : 25165824   .. 50331648
// wsp f16 [wq0,wq1,wk0,wk1,wp0,wp1] each 147456 elems: 50331648 .. 52101120
// y   f16 [t][b][n][c] : 52101120   .. 77266944
#define WS_X1   25165824
#define WS_WSP  50331648
#define WS_Y    52101120
#define WS_NEED 77266944

__device__ __forceinline__ void async16(void* lds, const void* g) {
    __builtin_amdgcn_global_load_lds(
        (const __attribute__((address_space(1))) unsigned int*)g,
        (__attribute__((address_space(3))) unsigned int*)lds, 16, 0, 0);
}

// ---------------------------------------------------------------------------
// prep: split 3 weight matrices into f16 hi/lo (layout preserved, c-contig)
// ---------------------------------------------------------------------------
__global__ __launch_bounds__(256) void wprep(
    const float* __restrict__ qw, const float* __restrict__ kw,
    const float* __restrict__ pw, _Float16* __restrict__ wsp)
{
    int gid = blockIdx.x * 256 + threadIdx.x;          // 0..110591
    int which = gid / 36864;
    int e4 = (gid % 36864) * 4;
    const float* src = (which == 0) ? qw : (which == 1) ? kw : pw;
    _Float16* d0 = wsp + (size_t)which * 294912;
    _Float16* d1 = d0 + 147456;
    float4 v = *(const float4*)(src + e4);
    f16x4 h0, h1;
    float vv[4] = {v.x, v.y, v.z, v.w};
#pragma unroll
    for (int j = 0; j < 4; ++j) {
        _Float16 a = (_Float16)vv[j];
        float r = vv[j] - (float)a;
        h0[j] = a; h1[j] = (_Float16)r;
    }
    *(f16x4*)(d0 + e4) = h0;
    *(f16x4*)(d1 + e4) = h1;
}

// ---------------------------------------------------------------------------
// prep: transpose + split x [t][b][c][n] fp32 -> x0,x1 f16 [t][b][n][c]
// grid: (T*B)*6*4 = 3072 blocks, 256 threads, 64x64 tiles
// ---------------------------------------------------------------------------
__global__ __launch_bounds__(256) void xprep(
    const float* __restrict__ x, _Float16* __restrict__ x0,
    _Float16* __restrict__ x1)
{
    __shared__ float xs[64 * 65];
    const int tid = threadIdx.x;
    int bid = blockIdx.x;
    int tb = bid / 24, r = bid % 24;
    int c0 = (r >> 2) * 64, n0 = (r & 3) * 64;

#pragma unroll
    for (int p = 0; p < 4; ++p) {
        int c = (tid >> 4) + p * 16;
        int nl = (tid & 15) * 4;
        float4 v = *(const float4*)&x[((size_t)tb * CC + c0 + c) * NN + n0 + nl];
        *(float4*)&xs[c * 65 + nl] = v;
    }
    __syncthreads();
    int n = tid >> 2, cg = (tid & 3) * 16;
#pragma unroll
    for (int j4 = 0; j4 < 4; ++j4) {
        int c = cg + j4 * 4;
        f16x4 h0, h1;
#pragma unroll
        for (int jj = 0; jj < 4; ++jj) {
            float v = xs[(c + jj) * 65 + n];
            _Float16 a = (_Float16)v;
            float rr = v - (float)a;
            h0[jj] = a; h1[jj] = (_Float16)rr;
        }
        size_t o = ((size_t)tb * NN + n0 + n) * CC + c0 + c;
        *(f16x4*)(x0 + o) = h0;
        *(f16x4*)(x1 + o) = h1;
    }
}

// ---------------------------------------------------------------------------
// Kernel A (MFMA): q/k GEMM + BN + LIF + head-sum + attn LIF + y=attn*k (f16)
// grid 512 = (b,head,nh) XCD-swizzled; 256 thr = 4 waves; wave: 48d x 32n
// ---------------------------------------------------------------------------
__global__ __launch_bounds__(256, 2) void qk_mfma(
    const _Float16* __restrict__ x0, const _Float16* __restrict__ x1,
    const _Float16* __restrict__ wsp,
    const float* __restrict__ qg, const float* __restrict__ qbe,
    const float* __restrict__ qm, const float* __restrict__ qva,
    const float* __restrict__ kg, const float* __restrict__ kbe,
    const float* __restrict__ km, const float* __restrict__ kva,
    _Float16* __restrict__ y)
{
    __shared__ __align__(16) _Float16 ldsW[12 * 512];   // 12 x 1KB frag tiles

    const int tid  = threadIdx.x;
    const int wave = tid >> 6;
    const int lane = tid & 63;
    const int m16  = lane & 15;
    const int quad = lane >> 4;

    // swizzle: 8 head-blocks sharing one (b,nh) x-slab land consecutively on one XCD
    int bid = blockIdx.x;
    int r8 = bid & 7, u = bid >> 3;
    int head = u & 7;
    int s = ((u >> 3) << 3) | r8;
    int b = s >> 1, nh = s & 1;

    const int n0 = nh * 128 + wave * 32;
    const int d0 = head * 48;

    f32x4 vq[3][2], vk[3][2];
    float va[2] = {0.f, 0.f};
#pragma unroll
    for (int dt = 0; dt < 3; ++dt)
#pragma unroll
        for (int nt = 0; nt < 2; ++nt) {
            vq[dt][nt] = (f32x4){0.f, 0.f, 0.f, 0.f};
            vk[dt][nt] = (f32x4){0.f, 0.f, 0.f, 0.f};
        }

    for (int tp = 0; tp < 2; ++tp) {
        f32x4 aq[2][3][2], ak[2][3][2];
#pragma unroll
        for (int t2 = 0; t2 < 2; ++t2)
#pragma unroll
            for (int dt = 0; dt < 3; ++dt)
#pragma unroll
                for (int nt = 0; nt < 2; ++nt) {
                    aq[t2][dt][nt] = (f32x4){0.f, 0.f, 0.f, 0.f};
                    ak[t2][dt][nt] = (f32x4){0.f, 0.f, 0.f, 0.f};
                }

        for (int kc = 0; kc < 12; ++kc) {
            const int c0 = kc * 32;
            __syncthreads();           // LDS free (prev readers done)
            // stage 12 weight frag tiles (q0,q1,k0,k1 x 3 dt), 3 per wave
#pragma unroll
            for (int p = 0; p < 3; ++p) {
                int i = wave + p * 4;
                int brs = i / 3, dt = i % 3;
                const _Float16* gsrc = wsp + (size_t)brs * 147456 +
                    (size_t)(d0 + dt * 16 + m16) * CC + c0 + quad * 8;
                async16(&ldsW[i * 512], gsrc);
            }
            // x B-frags direct to VGPR
            f16x8 bx[2][2][2];   // [t2][split][nt]
#pragma unroll
            for (int t2 = 0; t2 < 2; ++t2) {
                int t = tp * 2 + t2;
#pragma unroll
                for (int nt = 0; nt < 2; ++nt) {
                    size_t row = ((size_t)(t * BB + b) * NN + n0 + nt * 16 + m16) * CC
                                 + c0 + quad * 8;
                    bx[t2][0][nt] = *(const f16x8*)(x0 + row);
                    bx[t2][1][nt] = *(const f16x8*)(x1 + row);
                }
            }
            __syncthreads();           // staging complete
#pragma unroll
            for (int dt = 0; dt < 3; ++dt) {
                f16x8 wq0 = *(const f16x8*)&ldsW[(0 + dt) * 512 + lane * 8];
                f16x8 wq1 = *(const f16x8*)&ldsW[(3 + dt) * 512 + lane * 8];
                f16x8 wk0 = *(const f16x8*)&ldsW[(6 + dt) * 512 + lane * 8];
                f16x8 wk1 = *(const f16x8*)&ldsW[(9 + dt) * 512 + lane * 8];
#pragma unroll
                for (int t2 = 0; t2 < 2; ++t2)
#pragma unroll
                    for (int nt = 0; nt < 2; ++nt) {
                        f32x4 cq = aq[t2][dt][nt];
                        cq = __builtin_amdgcn_mfma_f32_16x16x32_f16(wq0, bx[t2][0][nt], cq, 0, 0, 0);
                        cq = __builtin_amdgcn_mfma_f32_16x16x32_f16(wq1, bx[t2][0][nt], cq, 0, 0, 0);
                        cq = __builtin_amdgcn_mfma_f32_16x16x32_f16(wq0, bx[t2][1][nt], cq, 0, 0, 0);
                        aq[t2][dt][nt] = cq;
                        f32x4 ck = ak[t2][dt][nt];
                        ck = __builtin_amdgcn_mfma_f32_16x16x32_f16(wk0, bx[t2][0][nt], ck, 0, 0, 0);
                        ck = __builtin_amdgcn_mfma_f32_16x16x32_f16(wk1, bx[t2][0][nt], ck, 0, 0, 0);
                        ck = __builtin_amdgcn_mfma_f32_16x16x32_f16(wk0, bx[t2][1][nt], ck, 0, 0, 0);
                        ak[t2][dt][nt] = ck;
                    }
            }
        }

        // epilogues: t = tp*2, tp*2+1 sequentially (LIF recurrence)
#pragma unroll
        for (int t2 = 0; t2 < 2; ++t2) {
            int t = tp * 2 + t2;
            float psum[2] = {0.f, 0.f};
            f32x4 ks[3][2];
#pragma unroll
            for (int dt = 0; dt < 3; ++dt) {
                int doff = d0 + dt * 16 + quad * 4;
                f32x4 gq = *(const f32x4*)(qg + doff);
                f32x4 bq = *(const f32x4*)(qbe + doff);
                f32x4 mq = *(const f32x4*)(qm + doff);
                f32x4 vq_ = *(const f32x4*)(qva + doff);
                f32x4 gk_ = *(const f32x4*)(kg + doff);
                f32x4 bk_ = *(const f32x4*)(kbe + doff);
                f32x4 mk_ = *(const f32x4*)(km + doff);
                f32x4 vk_ = *(const f32x4*)(kva + doff);
                float invq[4], invk[4];
#pragma unroll
                for (int rr = 0; rr < 4; ++rr) {
                    invq[rr] = gq[rr] / sqrtf(vq_[rr] + 1e-5f);
                    invk[rr] = gk_[rr] / sqrtf(vk_[rr] + 1e-5f);
                }
#pragma unroll
                for (int nt = 0; nt < 2; ++nt) {
#pragma unroll
                    for (int rr = 0; rr < 4; ++rr) {
                        float bnq = (aq[t2][dt][nt][rr] - mq[rr]) * invq[rr] + bq[rr];
                        float hq  = vq[dt][nt][rr] + (bnq - vq[dt][nt][rr]) * 0.5f;
                        float sq  = (hq - 1.0f >= 0.0f) ? 1.0f : 0.0f;
                        vq[dt][nt][rr] = hq * (1.0f - sq);
                        psum[nt] += sq;
                        float bnk = (ak[t2][dt][nt][rr] - mk_[rr]) * invk[rr] + bk_[rr];
                        float hk  = vk[dt][nt][rr] + (bnk - vk[dt][nt][rr]) * 0.5f;
                        float sk  = (hk - 1.0f >= 0.0f) ? 1.0f : 0.0f;
                        vk[dt][nt][rr] = hk * (1.0f - sk);
                        ks[dt][nt][rr] = sk;
                    }
                }
            }
            float attn[2];
#pragma unroll
            for (int nt = 0; nt < 2; ++nt) {
                float tot = psum[nt];
                tot += __shfl_xor(tot, 16, 64);   // sum over the 4 quads (48 d total)
                tot += __shfl_xor(tot, 32, 64);
                float ha = va[nt] + (tot - va[nt]) * 0.5f;
                float sa = (ha - 0.5f >= 0.0f) ? 1.0f : 0.0f;
                va[nt] = ha * (1.0f - sa);
                attn[nt] = sa;
            }
#pragma unroll
            for (int dt = 0; dt < 3; ++dt)
#pragma unroll
                for (int nt = 0; nt < 2; ++nt) {
                    f16x4 hv;
#pragma unroll
                    for (int rr = 0; rr < 4; ++rr)
                        hv[rr] = (_Float16)(attn[nt] * ks[dt][nt][rr]);
                    size_t off = ((size_t)(t * BB + b) * NN + n0 + nt * 16 + m16) * CC
                                 + d0 + dt * 16 + quad * 4;
                    *(f16x4*)(y + off) = hv;
                }
        }
    }
}

// ---------------------------------------------------------------------------
// Kernel B (MFMA): proj GEMM (y f16 exact) + bias + BN + LIF -> fp32 spikes
// grid 512 = (b,dg,nh) swizzled; 128 thr = 2 waves; wave: 48d x 64n
// ---------------------------------------------------------------------------
__global__ __launch_bounds__(128, 2) void proj_mfma(
    const _Float16* __restrict__ y,
    const _Float16* __restrict__ pw0, const _Float16* __restrict__ pw1,
    const float* __restrict__ pg, const float* __restrict__ pbe,
    const float* __restrict__ pm, const float* __restrict__ pva,
    const float* __restrict__ pbias, float* __restrict__ out)
{
    __shared__ __align__(16) _Float16 ldsW[6 * 512];

    const int tid  = threadIdx.x;
    const int wave = tid >> 6;
    const int lane = tid & 63;
    const int m16  = lane & 15;
    const int quad = lane >> 4;

    int bid = blockIdx.x;
    int r8 = bid & 7, u = bid >> 3;
    int dg = u & 7;
    int s = ((u >> 3) << 3) | r8;
    int b = s >> 1, nh = s & 1;

    const int n0 = nh * 128 + wave * 64;
    const int d0 = dg * 48;

    f32x4 vv[3][4];
#pragma unroll
    for (int dt = 0; dt < 3; ++dt)
#pragma unroll
        for (int nt = 0; nt < 4; ++nt) vv[dt][nt] = (f32x4){0.f, 0.f, 0.f, 0.f};

    for (int tp = 0; tp < 2; ++tp) {
        f32x4 acc[2][3][4];
#pragma unroll
        for (int t2 = 0; t2 < 2; ++t2)
#pragma unroll
            for (int dt = 0; dt < 3; ++dt)
#pragma unroll
                for (int nt = 0; nt < 4; ++nt)
                    acc[t2][dt][nt] = (f32x4){0.f, 0.f, 0.f, 0.f};

        for (int kc = 0; kc < 12; ++kc) {
            const int c0 = kc * 32;
            __syncthreads();
#pragma unroll
            for (int p = 0; p < 3; ++p) {
                int i = wave + p * 2;
                int sp = i / 3, dt = i % 3;
                const _Float16* src = (sp ? pw1 : pw0) +
                    (size_t)(d0 + dt * 16 + m16) * CC + c0 + quad * 8;
                async16(&ldsW[i * 512], src);
            }
            f16x8 by[2][4];
#pragma unroll
            for (int t2 = 0; t2 < 2; ++t2) {
                int t = tp * 2 + t2;
#pragma unroll
                for (int nt = 0; nt < 4; ++nt)
                    by[t2][nt] = *(const f16x8*)(y +
                        ((size_t)(t * BB + b) * NN + n0 + nt * 16 + m16) * CC +
                        c0 + quad * 8);
            }
            __syncthreads();
#pragma unroll
            for (int dt = 0; dt < 3; ++dt) {
                f16x8 a0 = *(const f16x8*)&ldsW[(0 + dt) * 512 + lane * 8];
                f16x8 a1 = *(const f16x8*)&ldsW[(3 + dt) * 512 + lane * 8];
#pragma unroll
                for (int t2 = 0; t2 < 2; ++t2)
#pragma unroll
                    for (int nt = 0; nt < 4; ++nt) {
                        f32x4 c = acc[t2][dt][nt];
                        c = __builtin_amdgcn_mfma_f32_16x16x32_f16(a0, by[t2][nt], c, 0, 0, 0);
                        c = __builtin_amdgcn_mfma_f32_16x16x32_f16(a1, by[t2][nt], c, 0, 0, 0);
                        acc[t2][dt][nt] = c;
                    }
            }
        }
#pragma unroll
        for (int t2 = 0; t2 < 2; ++t2) {
            int t = tp * 2 + t2;
#pragma unroll
            for (int dt = 0; dt < 3; ++dt) {
                int doff = d0 + dt * 16 + quad * 4;
                f32x4 g  = *(const f32x4*)(pg + doff);
                f32x4 be = *(const f32x4*)(pbe + doff);
                f32x4 mu = *(const f32x4*)(pm + doff);
                f32x4 va_ = *(const f32x4*)(pva + doff);
                f32x4 bi = *(const f32x4*)(pbias + doff);
                float inv[4];
#pragma unroll
                for (int rr = 0; rr < 4; ++rr)
                    inv[rr] = g[rr] / sqrtf(va_[rr] + 1e-5f);
#pragma unroll
                for (int nt = 0; nt < 4; ++nt) {
#pragma unroll
                    for (int rr = 0; rr < 4; ++rr) {
                        float z  = acc[t2][dt][nt][rr] + bi[rr];
                        float bn = (z - mu[rr]) * inv[rr] + be[rr];
                        float h  = vv[dt][nt][rr] + (bn - vv[dt][nt][rr]) * 0.5f;
                        float sp = (h - 1.0f >= 0.0f) ? 1.0f : 0.0f;
                        vv[dt][nt][rr] = h * (1.0f - sp);
                        out[((size_t)(t * BB + b) * CC + doff + rr) * NN +
                            n0 + nt * 16 + m16] = sp;
                    }
                }
            }
        }
    }
}

// ===========================================================================
// Fallback fp32 path (round-1, proven): used only if ws_size < WS_NEED
// ===========================================================================
#define KC 64
#define LSTR 68
__global__ __launch_bounds__(256) void qk_fused(
    const float* __restrict__ x,
    const float* __restrict__ qw, const float* __restrict__ qg,
    const float* __restrict__ qbe, const float* __restrict__ qm,
    const float* __restrict__ qva,
    const float* __restrict__ kw, const float* __restrict__ kg,
    const float* __restrict__ kbe, const float* __restrict__ km,
    const float* __restrict__ kva,
    unsigned char* __restrict__ y)
{
    __shared__ float xs[KC * LSTR];
    __shared__ float qws[48 * LSTR];
    __shared__ float kws[48 * LSTR];
    __shared__ float hsum[16 * 64];
    const int tid = threadIdx.x, bid = blockIdx.x;
    const int b = bid >> 5, head = (bid >> 2) & 7, n0 = (bid & 3) << 6;
    const int dg = tid >> 4, nl = (tid & 15) << 2;
    float q_inv[3], q_mu[3], q_b[3], k_inv[3], k_mu[3], k_b[3];
#pragma unroll
    for (int i = 0; i < 3; ++i) {
        int d = head * 48 + dg * 3 + i;
        q_inv[i] = qg[d] / sqrtf(qva[d] + 1e-5f); q_mu[i] = qm[d]; q_b[i] = qbe[d];
        k_inv[i] = kg[d] / sqrtf(kva[d] + 1e-5f); k_mu[i] = km[d]; k_b[i] = kbe[d];
    }
    float vq[3][4] = {}, vk[3][4] = {}, va[4] = {};
    for (int t = 0; t < TT; ++t) {
        float accq[3][4] = {}, acck[3][4] = {};
        for (int kc = 0; kc < CC / KC; ++kc) {
            const int c0 = kc * KC;
            __syncthreads();
#pragma unroll
            for (int p = 0; p < 4; ++p) {
                int q4 = tid + p * 256, cc = q4 >> 4, nn = (q4 & 15) << 2;
                *(float4*)&xs[cc * LSTR + nn] =
                    *(const float4*)&x[((size_t)(t * BB + b) * CC + c0 + cc) * NN + n0 + nn];
            }
#pragma unroll
            for (int p = 0; p < 3; ++p) {
                int q4 = tid + p * 256, dl = q4 >> 4, cc = (q4 & 15) << 2;
                *(float4*)&qws[dl * LSTR + cc] = *(const float4*)&qw[(head * 48 + dl) * CC + c0 + cc];
                *(float4*)&kws[dl * LSTR + cc] = *(const float4*)&kw[(head * 48 + dl) * CC + c0 + cc];
            }
            __syncthreads();
#pragma unroll
            for (int cq = 0; cq < KC / 4; ++cq) {
                float xv[4][4];
#pragma unroll
                for (int uu = 0; uu < 4; ++uu)
                    *(float4*)&xv[uu][0] = *(const float4*)&xs[(cq * 4 + uu) * LSTR + nl];
#pragma unroll
                for (int i = 0; i < 3; ++i) {
                    float qv[4], kv[4];
                    *(float4*)&qv[0] = *(const float4*)&qws[(dg * 3 + i) * LSTR + cq * 4];
                    *(float4*)&kv[0] = *(const float4*)&kws[(dg * 3 + i) * LSTR + cq * 4];
#pragma unroll
                    for (int uu = 0; uu < 4; ++uu)
#pragma unroll
                        for (int j = 0; j < 4; ++j) {
                            accq[i][j] = fmaf(qv[uu], xv[uu][j], accq[i][j]);
                            acck[i][j] = fmaf(kv[uu], xv[uu][j], acck[i][j]);
                        }
                }
            }
        }
        float part[4] = {0.f, 0.f, 0.f, 0.f};
        float ksp[3][4];
#pragma unroll
        for (int i = 0; i < 3; ++i)
#pragma unroll
            for (int j = 0; j < 4; ++j) {
                float bnq = (accq[i][j] - q_mu[i]) * q_inv[i] + q_b[i];
                float hq = vq[i][j] + (bnq - vq[i][j]) * 0.5f;
                float sq = (hq - 1.0f >= 0.0f) ? 1.0f : 0.0f;
                vq[i][j] = hq * (1.0f - sq); part[j] += sq;
                float bnk = (acck[i][j] - k_mu[i]) * k_inv[i] + k_b[i];
                float hk = vk[i][j] + (bnk - vk[i][j]) * 0.5f;
                float sk = (hk - 1.0f >= 0.0f) ? 1.0f : 0.0f;
                vk[i][j] = hk * (1.0f - sk); ksp[i][j] = sk;
            }
#pragma unroll
        for (int j = 0; j < 4; ++j) hsum[dg * 64 + nl + j] = part[j];
        __syncthreads();
        float attn[4];
#pragma unroll
        for (int j = 0; j < 4; ++j) {
            float tot = 0.f;
#pragma unroll
            for (int g = 0; g < 16; ++g) tot += hsum[g * 64 + nl + j];
            float ha = va[j] + (tot - va[j]) * 0.5f;
            float sa = (ha - 0.5f >= 0.0f) ? 1.0f : 0.0f;
            va[j] = ha * (1.0f - sa); attn[j] = sa;
        }
#pragma unroll
        for (int i = 0; i < 3; ++i) {
            uchar4 yo;
            yo.x = (unsigned char)(attn[0] * ksp[i][0]);
            yo.y = (unsigned char)(attn[1] * ksp[i][1]);
            yo.z = (unsigned char)(attn[2] * ksp[i][2]);
            yo.w = (unsigned char)(attn[3] * ksp[i][3]);
            *(uchar4*)&((unsigned char*)y)[((size_t)(t * BB + b) * CC + head * 48 + dg * 3 + i) * NN + n0 + nl] = yo;
        }
    }
}

__global__ __launch_bounds__(256) void proj_fused(
    const unsigned char* __restrict__ yin,
    const float* __restrict__ pw, const float* __restrict__ pg,
    const float* __restrict__ pbe, const float* __restrict__ pm,
    const float* __restrict__ pva, const float* __restrict__ pbias,
    float* __restrict__ out)
{
    __shared__ float ys[KC * LSTR];
    __shared__ float pws[64 * LSTR];
    const int tid = threadIdx.x, bid = blockIdx.x;
    const int b = bid / 24, r = bid % 24, d0 = (r >> 2) * 64, n0 = (r & 3) << 6;
    const int dg = tid >> 4, nl = (tid & 15) << 2;
    float inv[4], mu[4], be[4], bi[4];
#pragma unroll
    for (int i = 0; i < 4; ++i) {
        int d = d0 + dg * 4 + i;
        inv[i] = pg[d] / sqrtf(pva[d] + 1e-5f);
        mu[i] = pm[d]; be[i] = pbe[d]; bi[i] = pbias[d];
    }
    float vvv[4][4] = {};
    for (int t = 0; t < TT; ++t) {
        float acc[4][4] = {};
        for (int kc = 0; kc < CC / KC; ++kc) {
            const int c0 = kc * KC;
            __syncthreads();
#pragma unroll
            for (int p = 0; p < 4; ++p) {
                int q4 = tid + p * 256, cc = q4 >> 4, nn = (q4 & 15) << 2;
                unsigned int w = *(const unsigned int*)&yin[((size_t)(t * BB + b) * CC + c0 + cc) * NN + n0 + nn];
                ys[cc * LSTR + nn + 0] = (float)(w & 0xff);
                ys[cc * LSTR + nn + 1] = (float)((w >> 8) & 0xff);
                ys[cc * LSTR + nn + 2] = (float)((w >> 16) & 0xff);
                ys[cc * LSTR + nn + 3] = (float)(w >> 24);
                *(float4*)&pws[cc * LSTR + nn] = *(const float4*)&pw[(d0 + cc) * CC + c0 + nn];
            }
            __syncthreads();
#pragma unroll
            for (int cq = 0; cq < KC / 4; ++cq) {
                float xv[4][4];
#pragma unroll
                for (int uu = 0; uu < 4; ++uu)
                    *(float4*)&xv[uu][0] = *(const float4*)&ys[(cq * 4 + uu) * LSTR + nl];
#pragma unroll
                for (int i = 0; i < 4; ++i) {
                    float pv[4];
                    *(float4*)&pv[0] = *(const float4*)&pws[(dg * 4 + i) * LSTR + cq * 4];
#pragma unroll
                    for (int uu = 0; uu < 4; ++uu)
#pragma unroll
                        for (int j = 0; j < 4; ++j)
                            acc[i][j] = fmaf(pv[uu], xv[uu][j], acc[i][j]);
                }
            }
        }
#pragma unroll
        for (int i = 0; i < 4; ++i) {
            float res[4];
#pragma unroll
            for (int j = 0; j < 4; ++j) {
                float z = acc[i][j] + bi[i];
                float bnv = (z - mu[i]) * inv[i] + be[i];
                float h = vvv[i][j] + (bnv - vvv[i][j]) * 0.5f;
                float sx = (h - 1.0f >= 0.0f) ? 1.0f : 0.0f;
                vvv[i][j] = h * (1.0f - sx);
                res[j] = sx;
            }
            *(float4*)&out[((size_t)(t * BB + b) * CC + d0 + dg * 4 + i) * NN + n0 + nl] = *(float4*)&res[0];
        }
    }
}

extern "C" void kernel_launch(void* const* d_in, const int* in_sizes, int n_in,
                              void* d_out, int out_size, void* d_ws, size_t ws_size,
                              hipStream_t stream)
{
    const float* x     = (const float*)d_in[0];
    const float* qw    = (const float*)d_in[1];
    const float* qg    = (const float*)d_in[2];
    const float* qbe   = (const float*)d_in[3];
    const float* qm    = (const float*)d_in[4];
    const float* qva   = (const float*)d_in[5];
    const float* kw    = (const float*)d_in[6];
    const float* kg    = (const float*)d_in[7];
    const float* kbe   = (const float*)d_in[8];
    const float* km    = (const float*)d_in[9];
    const float* kva   = (const float*)d_in[10];
    const float* pw    = (const float*)d_in[11];
    const float* pg    = (const float*)d_in[12];
    const float* pbe   = (const float*)d_in[13];
    const float* pm    = (const float*)d_in[14];
    const float* pva   = (const float*)d_in[15];
    const float* pbias = (const float*)d_in[16];
    float* out = (float*)d_out;

    if (ws_size >= (size_t)WS_NEED) {
        char* w = (char*)d_ws;
        _Float16* x0  = (_Float16*)(w);
        _Float16* x1  = (_Float16*)(w + WS_X1);
        _Float16* wsp = (_Float16*)(w + WS_WSP);
        _Float16* pw0 = wsp + 4 * 147456;
        _Float16* pw1 = wsp + 5 * 147456;
        _Float16* yf  = (_Float16*)(w + WS_Y);

        wprep<<<432, 256, 0, stream>>>(qw, kw, pw, wsp);
        xprep<<<3072, 256, 0, stream>>>(x, x0, x1);
        qk_mfma<<<512, 256, 0, stream>>>(x0, x1, wsp, qg, qbe, qm, qva,
                                         kg, kbe, km, kva, yf);
        proj_mfma<<<512, 128, 0, stream>>>(yf, pw0, pw1, pg, pbe, pm, pva,
                                           pbias, out);
    } else {
        unsigned char* y = (unsigned char*)d_ws;
        qk_fused<<<BB * 8 * (NN / 64), 256, 0, stream>>>(
            x, qw, qg, qbe, qm, qva, kw, kg, kbe, km, kva, y);
        proj_fused<<<BB * (CC / 64) * (NN / 64), 256, 0, stream>>>(
            y, pw, pg, pbe, pm, pva, pbias, out);
    }
}